// Round 2
// baseline (995.821 us; speedup 1.0000x reference)
//
#include <hip/hip_runtime.h>

#define NN 50000
#define NC 64
#define NE 800000

// ---------------------------------------------------------------------------
// Kernel 0: zero a float buffer (harness poisons d_out/d_ws to 0xAA each call)
// ---------------------------------------------------------------------------
__global__ void zero_kernel(float* __restrict__ p, int n) {
    int i = blockIdx.x * blockDim.x + threadIdx.x;
    if (i < n) p[i] = 0.0f;
}

// ---------------------------------------------------------------------------
// Kernel 1: scatter-add x[row[e]] into out[col[e]] (out doubles as aggr),
// count degree. 16 threads/edge, float4 gather (coalesced 256 B per edge).
// ---------------------------------------------------------------------------
__global__ __launch_bounds__(256) void scatter_kernel(
        const float4* __restrict__ x4,
        const int*    __restrict__ row,
        const int*    __restrict__ col,
        float*        __restrict__ aggr,   // = d_out
        float*        __restrict__ deg) {
    int gid = blockIdx.x * blockDim.x + threadIdx.x;   // [0, NE*16)
    int e = gid >> 4;
    int g = gid & 15;
    int r = row[e];
    int c = col[e];
    float4 v = x4[r * (NC / 4) + g];
    float* dst = aggr + c * NC + g * 4;
    atomicAdd(dst + 0, v.x);
    atomicAdd(dst + 1, v.y);
    atomicAdd(dst + 2, v.z);
    atomicAdd(dst + 3, v.w);
    if (g == 0) atomicAdd(deg + c, 1.0f);
}

// ---------------------------------------------------------------------------
// Kernel 2 (in place): out[n][o] = b[o] + sum_c x[n][c]*W[o][c]
//                                + sum_c (aggr[n][c]/max(deg,1))*W[o][64+c]
// aggr lives in out[] on entry; each block stages its 4 rows into LDS,
// syncs, then overwrites them. Blocks own disjoint rows -> race-free.
// W staged transposed in LDS: Wt[c][o], lane(=o)-consecutive (conflict-free).
// ---------------------------------------------------------------------------
__global__ __launch_bounds__(256) void linear_kernel(
        const float* __restrict__ x,
        float*       __restrict__ out,     // holds aggr on entry
        const float* __restrict__ deg,
        const float* __restrict__ W,
        const float* __restrict__ b) {
    __shared__ float Wt[2 * NC * NC];   // [128][64] = 32 KB
    __shared__ float sa[4 * NC];        // this block's 4 aggr rows
    for (int i = threadIdx.x; i < 2 * NC * NC; i += 256) {
        int o = i >> 7;        // W is [64][128] row-major
        int c = i & 127;
        Wt[c * NC + o] = W[i];
    }

    int o  = threadIdx.x & 63;
    int ln = threadIdx.x >> 6;
    int n  = blockIdx.x * 4 + ln;

    float av = 0.0f, degv = 1.0f;
    if (n < NN) {
        av   = out[n * NC + o];
        degv = deg[n];
    }
    sa[ln * NC + o] = av;
    __syncthreads();           // all aggr reads done before any out write
    if (n >= NN) return;

    float inv = 1.0f / fmaxf(degv, 1.0f);
    const float* xr = x + n * NC;

    float acc = b[o];
#pragma unroll
    for (int c = 0; c < NC; ++c)
        acc = fmaf(xr[c], Wt[c * NC + o], acc);
#pragma unroll
    for (int c = 0; c < NC; ++c)
        acc = fmaf(sa[ln * NC + c] * inv, Wt[(NC + c) * NC + o], acc);

    out[n * NC + o] = acc;
}

// ---------------------------------------------------------------------------
extern "C" void kernel_launch(void* const* d_in, const int* in_sizes, int n_in,
                              void* d_out, int out_size, void* d_ws, size_t ws_size,
                              hipStream_t stream) {
    const float* x   = (const float*)d_in[0];
    const int*   ei  = (const int*)d_in[1];     // [2, NE] flattened
    const float* W   = (const float*)d_in[2];   // [64, 128]
    const float* b   = (const float*)d_in[3];   // [64]
    float*       out = (float*)d_out;

    const int* row = ei;          // source nodes
    const int* col = ei + NE;     // destination nodes

    float* deg = (float*)d_ws;    // [NN] — only 200 KB of ws used

    // 0) zero the accumulator (d_out) and deg
    zero_kernel<<<(NN * NC + 255) / 256, 256, 0, stream>>>(out, NN * NC);
    zero_kernel<<<(NN + 255) / 256, 256, 0, stream>>>(deg, NN);

    // 1) scatter-add into d_out (NE*16 threads = exactly 50000 blocks of 256)
    scatter_kernel<<<(NE * 16) / 256, 256, 0, stream>>>(
        (const float4*)x, row, col, out, deg);

    // 2) fused mean + concat + linear, in place on d_out
    linear_kernel<<<NN / 4, 256, 0, stream>>>(x, out, deg, W, b);
}

// Round 3
// 495.121 us; speedup vs baseline: 2.0113x; 2.0113x over previous
//
#include <hip/hip_runtime.h>

#define NN 50000
#define NC 64
#define NE 800000
#define SCAN_T 1024

// ---------------------------------------------------------------------------
// Kernel 1: count in-degree of each destination node (int atomics, L2-resident)
// ---------------------------------------------------------------------------
__global__ __launch_bounds__(256) void count_kernel(
        const int* __restrict__ col, int* __restrict__ cnt) {
    int e = blockIdx.x * blockDim.x + threadIdx.x;
    if (e < NE) atomicAdd(&cnt[col[e]], 1);
}

// ---------------------------------------------------------------------------
// Kernel 2: single-block exclusive scan of cnt[NN] -> off[NN+1]
// 1024 threads, chunk-serial + Hillis-Steele on 1024 partials in LDS.
// ---------------------------------------------------------------------------
__global__ __launch_bounds__(SCAN_T) void scan_kernel(
        const int* __restrict__ cnt, int* __restrict__ off) {
    __shared__ int part[SCAN_T];
    int t = threadIdx.x;
    const int CH = (NN + SCAN_T - 1) / SCAN_T;   // 49
    int lo = t * CH;
    int hi = lo + CH; if (hi > NN) hi = NN;
    int s = 0;
    for (int i = lo; i < hi; ++i) s += cnt[i];
    part[t] = s;
    __syncthreads();
    for (int d = 1; d < SCAN_T; d <<= 1) {
        int v = (t >= d) ? part[t - d] : 0;
        __syncthreads();
        part[t] += v;
        __syncthreads();
    }
    int run = (t == 0) ? 0 : part[t - 1];        // exclusive base for my chunk
    for (int i = lo; i < hi; ++i) {
        off[i] = run;
        run += cnt[i];
    }
    if (t == SCAN_T - 1) off[NN] = run;          // total == NE
}

// ---------------------------------------------------------------------------
// Kernel 3: CSR fill — perm[off[c] + cursor[c]++] = row[e]
// ---------------------------------------------------------------------------
__global__ __launch_bounds__(256) void fill_kernel(
        const int* __restrict__ row, const int* __restrict__ col,
        const int* __restrict__ off, int* __restrict__ cursor,
        int* __restrict__ perm) {
    int e = blockIdx.x * blockDim.x + threadIdx.x;
    if (e < NE) {
        int c = col[e];
        int p = atomicAdd(&cursor[c], 1);
        perm[off[c] + p] = row[e];
    }
}

// ---------------------------------------------------------------------------
// Kernel 4: fused gather + mean + concat + linear.
// Block = 256 = 4 waves; one wave per dst node, lane = channel.
// Neighbor rows x[src][:] are coalesced 256 B reads (L2/LLC-resident).
// Mean + self row round-trip through LDS; W staged transposed (Wt[c][o],
// lane-consecutive => conflict-free; broadcast reads of sx/sa are free).
// Grid is exactly NN/4 blocks -> no bounds guards, barrier-safe.
// ---------------------------------------------------------------------------
__global__ __launch_bounds__(256) void gather_linear_kernel(
        const float* __restrict__ x,
        const int*   __restrict__ off,
        const int*   __restrict__ perm,
        const float* __restrict__ W,
        const float* __restrict__ b,
        float*       __restrict__ out) {
    __shared__ float Wt[2 * NC * NC];   // 32 KB: Wt[c*64+o] = W[o*128+c]
    __shared__ float sx[4][NC];
    __shared__ float sa[4][NC];
    for (int i = threadIdx.x; i < 2 * NC * NC; i += 256) {
        int o = i >> 7;                  // W is [64][128] row-major
        int c = i & 127;
        Wt[c * NC + o] = W[i];
    }

    int lane = threadIdx.x & 63;
    int w    = threadIdx.x >> 6;
    int n    = blockIdx.x * 4 + w;       // always < NN (grid = NN/4 exactly)

    int beg = off[n], end = off[n + 1];
    float acc = 0.0f;
    for (int i = beg; i < end; ++i) {
        int src = perm[i];               // wave-uniform -> scalar load
        acc += x[src * NC + lane];       // 256 B coalesced per wave
    }
    float inv = 1.0f / fmaxf((float)(end - beg), 1.0f);
    sa[w][lane] = acc * inv;
    sx[w][lane] = x[n * NC + lane];
    __syncthreads();                     // covers Wt staging + sa/sx cross-lane

    float acc2 = b[lane];
#pragma unroll
    for (int c = 0; c < NC; ++c) {
        acc2 = fmaf(sx[w][c], Wt[c * NC + lane], acc2);
        acc2 = fmaf(sa[w][c], Wt[(NC + c) * NC + lane], acc2);
    }
    out[n * NC + lane] = acc2;
}

// ---------------------------------------------------------------------------
extern "C" void kernel_launch(void* const* d_in, const int* in_sizes, int n_in,
                              void* d_out, int out_size, void* d_ws, size_t ws_size,
                              hipStream_t stream) {
    const float* x   = (const float*)d_in[0];
    const int*   ei  = (const int*)d_in[1];     // [2, NE] flattened
    const float* W   = (const float*)d_in[2];   // [64, 128]
    const float* b   = (const float*)d_in[3];   // [64]
    float*       out = (float*)d_out;

    const int* row = ei;          // source nodes
    const int* col = ei + NE;     // destination nodes

    // workspace layout (ints): cnt[NN] | off[NN+1] | cursor[NN] | perm[NE]
    int* cnt    = (int*)d_ws;
    int* off    = cnt + NN;
    int* cursor = off + NN + 1;
    int* perm   = cursor + NN;    // total ~3.8 MB

    hipMemsetAsync(cnt, 0, NN * sizeof(int), stream);
    hipMemsetAsync(cursor, 0, NN * sizeof(int), stream);

    count_kernel<<<(NE + 255) / 256, 256, 0, stream>>>(col, cnt);
    scan_kernel<<<1, SCAN_T, 0, stream>>>(cnt, off);
    fill_kernel<<<(NE + 255) / 256, 256, 0, stream>>>(row, col, off, cursor, perm);
    gather_linear_kernel<<<NN / 4, 256, 0, stream>>>(x, off, perm, W, b, out);
}

// Round 4
// 381.145 us; speedup vs baseline: 2.6127x; 1.2990x over previous
//
#include <hip/hip_runtime.h>

#define NN 50000
#define NC 64
#define NE 800000
#define NQUAD (NN / 4)          // 12500 4-node work items

// ---------------------------------------------------------------------------
// Kernel 1: count in-degree — 4 edges/thread via int4 (coalesced 16B loads)
// ---------------------------------------------------------------------------
__global__ __launch_bounds__(256) void count_kernel(
        const int4* __restrict__ col4, int* __restrict__ cnt) {
    int t = blockIdx.x * blockDim.x + threadIdx.x;
    if (t < NE / 4) {
        int4 c = col4[t];
        atomicAdd(&cnt[c.x], 1);
        atomicAdd(&cnt[c.y], 1);
        atomicAdd(&cnt[c.z], 1);
        atomicAdd(&cnt[c.w], 1);
    }
}

// ---------------------------------------------------------------------------
// Kernel 2a: per-block sums of cnt (coalesced), 196 blocks
// ---------------------------------------------------------------------------
__global__ __launch_bounds__(256) void bsum_kernel(
        const int* __restrict__ cnt, int* __restrict__ bsum) {
    int i = blockIdx.x * 256 + threadIdx.x;
    int v = (i < NN) ? cnt[i] : 0;
#pragma unroll
    for (int d = 32; d > 0; d >>= 1) v += __shfl_down(v, d, 64);
    __shared__ int wsum[4];
    if ((threadIdx.x & 63) == 0) wsum[threadIdx.x >> 6] = v;
    __syncthreads();
    if (threadIdx.x == 0)
        bsum[blockIdx.x] = wsum[0] + wsum[1] + wsum[2] + wsum[3];
}

// ---------------------------------------------------------------------------
// Kernel 2b: 1-block exclusive scan of 196 block sums
// ---------------------------------------------------------------------------
__global__ __launch_bounds__(256) void scan_bsum_kernel(
        const int* __restrict__ bsum, int* __restrict__ boff, int nblk) {
    __shared__ int s[256];
    int t = threadIdx.x;
    int v = (t < nblk) ? bsum[t] : 0;
    s[t] = v;
    __syncthreads();
#pragma unroll
    for (int d = 1; d < 256; d <<= 1) {
        int u = (t >= d) ? s[t - d] : 0;
        __syncthreads();
        s[t] += u;
        __syncthreads();
    }
    if (t < nblk) boff[t] = s[t] - v;   // exclusive
}

// ---------------------------------------------------------------------------
// Kernel 2c: off[i] = boff[blk] + block-local exclusive scan of cnt
// ---------------------------------------------------------------------------
__global__ __launch_bounds__(256) void apply_off_kernel(
        const int* __restrict__ cnt, const int* __restrict__ boff,
        int* __restrict__ off) {
    int b = blockIdx.x, t = threadIdx.x;
    int i = b * 256 + t;
    int v = (i < NN) ? cnt[i] : 0;
    __shared__ int s[256];
    s[t] = v;
    __syncthreads();
#pragma unroll
    for (int d = 1; d < 256; d <<= 1) {
        int u = (t >= d) ? s[t - d] : 0;
        __syncthreads();
        s[t] += u;
        __syncthreads();
    }
    int excl = s[t] - v;
    if (i < NN) off[i] = boff[b] + excl;
    if (i == NN - 1) off[NN] = boff[b] + excl + v;   // == NE
}

// ---------------------------------------------------------------------------
// Kernel 3: CSR fill — 4 edges/thread, int atomic cursors
// ---------------------------------------------------------------------------
__global__ __launch_bounds__(256) void fill_kernel(
        const int4* __restrict__ row4, const int4* __restrict__ col4,
        const int* __restrict__ off, int* __restrict__ cursor,
        int* __restrict__ perm) {
    int t = blockIdx.x * blockDim.x + threadIdx.x;
    if (t < NE / 4) {
        int4 r = row4[t];
        int4 c = col4[t];
        perm[off[c.x] + atomicAdd(&cursor[c.x], 1)] = r.x;
        perm[off[c.y] + atomicAdd(&cursor[c.y], 1)] = r.y;
        perm[off[c.z] + atomicAdd(&cursor[c.z], 1)] = r.z;
        perm[off[c.w] + atomicAdd(&cursor[c.w], 1)] = r.w;
    }
}

// ---------------------------------------------------------------------------
// Kernel 4: persistent fused gather + mean + concat + linear.
// Block = 4 waves; each wave pulls a 4-node quad from a global atomic queue
// (perfect balance). W staged ONCE per block as float4 Wq[c4*64+o] (b128,
// conflict-free). Gather: 4 independent perm->x chains (MLP x4), scalarized
// uniform loads. Linear: b128 Wq reads amortized over 4 nodes; aggr rows
// broadcast via per-wave LDS (in-wave DS-pipe ordering, no barrier needed);
// self rows read directly from global (wave-uniform address).
// ---------------------------------------------------------------------------
__global__ __launch_bounds__(256) void gather_linear_kernel(
        const float*  __restrict__ x,
        const float4* __restrict__ x4,
        const int*    __restrict__ off,
        const int*    __restrict__ perm,
        const float4* __restrict__ W4,     // [64][32] float4 view of [64][128]
        const float*  __restrict__ b,
        int*          __restrict__ ctr,
        float*        __restrict__ out) {
    __shared__ float4 Wq[32 * 64];         // 32 KB: Wq[c4*64+o] = W[o][4c4..+3]
    __shared__ float4 saq[4][4][16];       // 4 KB: per-wave, per-node aggr row
    for (int idx = threadIdx.x; idx < 2048; idx += 256) {
        int o = idx & 63, c4 = idx >> 6;
        Wq[c4 * 64 + o] = W4[o * 32 + c4];
    }
    __syncthreads();

    int lane = threadIdx.x & 63;
    int w    = threadIdx.x >> 6;
    float bv = b[lane];

    for (;;) {
        int q = 0;
        if (lane == 0) q = atomicAdd(ctr, 1);
        q = __shfl(q, 0, 64);
        if (q >= NQUAD) break;
        int n0 = __builtin_amdgcn_readfirstlane(q * 4);

        int o0 = off[n0], o1 = off[n0 + 1], o2 = off[n0 + 2],
            o3 = off[n0 + 3], o4 = off[n0 + 4];
        int d0 = o1 - o0, d1 = o2 - o1, d2 = o3 - o2, d3 = o4 - o3;
        int m = max(max(d0, d1), max(d2, d3));

        float a0 = 0.f, a1 = 0.f, a2 = 0.f, a3 = 0.f;
        for (int d = 0; d < m; ++d) {       // 4 independent load chains
            if (d < d0) a0 += x[perm[o0 + d] * NC + lane];
            if (d < d1) a1 += x[perm[o1 + d] * NC + lane];
            if (d < d2) a2 += x[perm[o2 + d] * NC + lane];
            if (d < d3) a3 += x[perm[o3 + d] * NC + lane];
        }
        a0 *= 1.0f / fmaxf((float)d0, 1.0f);
        a1 *= 1.0f / fmaxf((float)d1, 1.0f);
        a2 *= 1.0f / fmaxf((float)d2, 1.0f);
        a3 *= 1.0f / fmaxf((float)d3, 1.0f);
        ((float*)&saq[w][0][0])[lane] = a0;   // lane-consecutive, 2-way = free
        ((float*)&saq[w][1][0])[lane] = a1;
        ((float*)&saq[w][2][0])[lane] = a2;
        ((float*)&saq[w][3][0])[lane] = a3;
        // no __syncthreads: same-wave LDS write->read, DS pipe is in-order

        float c0 = bv, c1 = bv, c2 = bv, c3 = bv;
#pragma unroll 4
        for (int k = 0; k < 16; ++k) {      // self part: W[:, 0:64]
            float4 wv = Wq[k * 64 + lane];
            float4 v0 = x4[(n0 + 0) * 16 + k];   // wave-uniform -> scalar ld
            float4 v1 = x4[(n0 + 1) * 16 + k];
            float4 v2 = x4[(n0 + 2) * 16 + k];
            float4 v3 = x4[(n0 + 3) * 16 + k];
            c0 = fmaf(wv.x, v0.x, fmaf(wv.y, v0.y, fmaf(wv.z, v0.z, fmaf(wv.w, v0.w, c0))));
            c1 = fmaf(wv.x, v1.x, fmaf(wv.y, v1.y, fmaf(wv.z, v1.z, fmaf(wv.w, v1.w, c1))));
            c2 = fmaf(wv.x, v2.x, fmaf(wv.y, v2.y, fmaf(wv.z, v2.z, fmaf(wv.w, v2.w, c2))));
            c3 = fmaf(wv.x, v3.x, fmaf(wv.y, v3.y, fmaf(wv.z, v3.z, fmaf(wv.w, v3.w, c3))));
        }
#pragma unroll 4
        for (int k = 0; k < 16; ++k) {      // aggr part: W[:, 64:128]
            float4 wv = Wq[(16 + k) * 64 + lane];
            float4 v0 = saq[w][0][k];            // broadcast reads = free
            float4 v1 = saq[w][1][k];
            float4 v2 = saq[w][2][k];
            float4 v3 = saq[w][3][k];
            c0 = fmaf(wv.x, v0.x, fmaf(wv.y, v0.y, fmaf(wv.z, v0.z, fmaf(wv.w, v0.w, c0))));
            c1 = fmaf(wv.x, v1.x, fmaf(wv.y, v1.y, fmaf(wv.z, v1.z, fmaf(wv.w, v1.w, c1))));
            c2 = fmaf(wv.x, v2.x, fmaf(wv.y, v2.y, fmaf(wv.z, v2.z, fmaf(wv.w, v2.w, c2))));
            c3 = fmaf(wv.x, v3.x, fmaf(wv.y, v3.y, fmaf(wv.z, v3.z, fmaf(wv.w, v3.w, c3))));
        }
        out[(n0 + 0) * NC + lane] = c0;
        out[(n0 + 1) * NC + lane] = c1;
        out[(n0 + 2) * NC + lane] = c2;
        out[(n0 + 3) * NC + lane] = c3;
    }
}

// ---------------------------------------------------------------------------
extern "C" void kernel_launch(void* const* d_in, const int* in_sizes, int n_in,
                              void* d_out, int out_size, void* d_ws, size_t ws_size,
                              hipStream_t stream) {
    const float* x   = (const float*)d_in[0];
    const int*   ei  = (const int*)d_in[1];     // [2, NE] flattened
    const float* W   = (const float*)d_in[2];   // [64, 128]
    const float* b   = (const float*)d_in[3];   // [64]
    float*       out = (float*)d_out;

    const int* row = ei;          // source nodes
    const int* col = ei + NE;     // destination nodes

    // ws layout (ints): cnt[NN] | cursor[NN] | ctr[1] | off[NN+1] |
    //                   bsum[196] | boff[196] | perm[NE]   (~3.8 MB total)
    int* cnt    = (int*)d_ws;
    int* cursor = cnt + NN;
    int* ctr    = cursor + NN;
    int* off    = ctr + 1;
    int* bsum   = off + NN + 1;
    int* boff   = bsum + 196;
    int* perm   = boff + 196;

    hipMemsetAsync(cnt, 0, (2 * NN + 1) * sizeof(int), stream);  // cnt+cursor+ctr

    count_kernel<<<(NE / 4 + 255) / 256, 256, 0, stream>>>((const int4*)col, cnt);
    bsum_kernel<<<(NN + 255) / 256, 256, 0, stream>>>(cnt, bsum);
    scan_bsum_kernel<<<1, 256, 0, stream>>>(bsum, boff, (NN + 255) / 256);
    apply_off_kernel<<<(NN + 255) / 256, 256, 0, stream>>>(cnt, boff, off);
    fill_kernel<<<(NE / 4 + 255) / 256, 256, 0, stream>>>(
        (const int4*)row, (const int4*)col, off, cursor, perm);
    gather_linear_kernel<<<1024, 256, 0, stream>>>(
        x, (const float4*)x, off, perm, (const float4*)W, b, ctr, out);
}

// Round 5
// 218.008 us; speedup vs baseline: 4.5678x; 1.7483x over previous
//
#include <hip/hip_runtime.h>

#define NN 50000
#define NC 64
#define NE 800000
#define NQUAD (NN / 4)          // 12500 4-node work items
#define GBLK 1042               // 4168 waves -> 3 quads/wave (near-perfect)
#define NWAVES (GBLK * 4)

// ---------------------------------------------------------------------------
// Kernel 1: count in-degree — 4 edges/thread via int4 (coalesced 16B loads)
// ---------------------------------------------------------------------------
__global__ __launch_bounds__(256) void count_kernel(
        const int4* __restrict__ col4, int* __restrict__ cnt) {
    int t = blockIdx.x * blockDim.x + threadIdx.x;
    if (t < NE / 4) {
        int4 c = col4[t];
        atomicAdd(&cnt[c.x], 1);
        atomicAdd(&cnt[c.y], 1);
        atomicAdd(&cnt[c.z], 1);
        atomicAdd(&cnt[c.w], 1);
    }
}

// ---------------------------------------------------------------------------
// Kernel 2a: per-block sums of cnt (coalesced), 196 blocks
// ---------------------------------------------------------------------------
__global__ __launch_bounds__(256) void bsum_kernel(
        const int* __restrict__ cnt, int* __restrict__ bsum) {
    int i = blockIdx.x * 256 + threadIdx.x;
    int v = (i < NN) ? cnt[i] : 0;
#pragma unroll
    for (int d = 32; d > 0; d >>= 1) v += __shfl_down(v, d, 64);
    __shared__ int wsum[4];
    if ((threadIdx.x & 63) == 0) wsum[threadIdx.x >> 6] = v;
    __syncthreads();
    if (threadIdx.x == 0)
        bsum[blockIdx.x] = wsum[0] + wsum[1] + wsum[2] + wsum[3];
}

// ---------------------------------------------------------------------------
// Kernel 2b: 1-block exclusive scan of 196 block sums
// ---------------------------------------------------------------------------
__global__ __launch_bounds__(256) void scan_bsum_kernel(
        const int* __restrict__ bsum, int* __restrict__ boff, int nblk) {
    __shared__ int s[256];
    int t = threadIdx.x;
    int v = (t < nblk) ? bsum[t] : 0;
    s[t] = v;
    __syncthreads();
#pragma unroll
    for (int d = 1; d < 256; d <<= 1) {
        int u = (t >= d) ? s[t - d] : 0;
        __syncthreads();
        s[t] += u;
        __syncthreads();
    }
    if (t < nblk) boff[t] = s[t] - v;   // exclusive
}

// ---------------------------------------------------------------------------
// Kernel 2c: off[i] = boff[blk] + block-local exclusive scan of cnt
// ---------------------------------------------------------------------------
__global__ __launch_bounds__(256) void apply_off_kernel(
        const int* __restrict__ cnt, const int* __restrict__ boff,
        int* __restrict__ off) {
    int b = blockIdx.x, t = threadIdx.x;
    int i = b * 256 + t;
    int v = (i < NN) ? cnt[i] : 0;
    __shared__ int s[256];
    s[t] = v;
    __syncthreads();
#pragma unroll
    for (int d = 1; d < 256; d <<= 1) {
        int u = (t >= d) ? s[t - d] : 0;
        __syncthreads();
        s[t] += u;
        __syncthreads();
    }
    int excl = s[t] - v;
    if (i < NN) off[i] = boff[b] + excl;
    if (i == NN - 1) off[NN] = boff[b] + excl + v;   // == NE
}

// ---------------------------------------------------------------------------
// Kernel 3: CSR fill — 4 edges/thread, int atomic cursors
// ---------------------------------------------------------------------------
__global__ __launch_bounds__(256) void fill_kernel(
        const int4* __restrict__ row4, const int4* __restrict__ col4,
        const int* __restrict__ off, int* __restrict__ cursor,
        int* __restrict__ perm) {
    int t = blockIdx.x * blockDim.x + threadIdx.x;
    if (t < NE / 4) {
        int4 r = row4[t];
        int4 c = col4[t];
        perm[off[c.x] + atomicAdd(&cursor[c.x], 1)] = r.x;
        perm[off[c.y] + atomicAdd(&cursor[c.y], 1)] = r.y;
        perm[off[c.z] + atomicAdd(&cursor[c.z], 1)] = r.z;
        perm[off[c.w] + atomicAdd(&cursor[c.w], 1)] = r.w;
    }
}

// ---------------------------------------------------------------------------
// Kernel 4: fused gather + mean + concat + linear, branch-free float4 gather.
// One wave per 4-node quad (static strided). Lane = (edge-slot g = lane>>4,
// chunk c4 = lane&15). Per iteration: 4 perm + 4 x4 loads, ALL unconditional
// (cndmask on addr/weight, no branches) -> 16 edges in flight per wave.
// Cross-group reduce via shfl_xor(32/16). W staged once/block as float4
// (b128, conflict-free). Node rows round-trip LDS (same-wave, no barrier).
// ---------------------------------------------------------------------------
__global__ __launch_bounds__(256) void gather_linear_kernel(
        const float4* __restrict__ x4,
        const int*    __restrict__ off,
        const int*    __restrict__ perm,
        const float4* __restrict__ W4,     // [64][32] float4 view of [64][128]
        const float*  __restrict__ b,
        float*        __restrict__ out) {
    __shared__ float4 Wq[32 * 64];         // 32 KB: Wq[c4*64+o] = W[o][4c4..+3]
    __shared__ float4 sq[4][8][16];        // 8 KB: [wave][0-3 aggr | 4-7 self]
    for (int idx = threadIdx.x; idx < 2048; idx += 256) {
        int o = idx & 63, c = idx >> 6;
        Wq[c * 64 + o] = W4[o * 32 + c];
    }
    __syncthreads();

    const int lane = threadIdx.x & 63;
    const int w    = threadIdx.x >> 6;
    const int g    = lane >> 4;            // edge slot 0..3
    const int c4   = lane & 15;            // float4 chunk 0..15
    const float bv = b[lane];

    for (int q = blockIdx.x * 4 + w; q < NQUAD; q += NWAVES) {
        const int n0 = __builtin_amdgcn_readfirstlane(q * 4);
        int o0 = off[n0 + 0], o1 = off[n0 + 1], o2 = off[n0 + 2],
            o3 = off[n0 + 3], o4 = off[n0 + 4];
        int d0 = o1 - o0, d1 = o2 - o1, d2 = o3 - o2, d3 = o4 - o3;
        int m  = max(max(d0, d1), max(d2, d3));
        int itn = (m + 3) >> 2;

        // self rows: one vectorized load — lane-group g grabs node g's row
        float4 sv = x4[(n0 + g) * 16 + c4];

        float4 A0 = make_float4(0.f, 0.f, 0.f, 0.f);
        float4 A1 = A0, A2 = A0, A3 = A0;
        for (int it = 0, e = g; it < itn; ++it, e += 4) {
            int i0 = (e < d0) ? o0 + e : 0;      // cndmask, no branch
            int i1 = (e < d1) ? o1 + e : 0;
            int i2 = (e < d2) ? o2 + e : 0;
            int i3 = (e < d3) ? o3 + e : 0;
            int s0 = perm[i0], s1 = perm[i1], s2 = perm[i2], s3 = perm[i3];
            float w0 = (e < d0) ? 1.f : 0.f;
            float w1 = (e < d1) ? 1.f : 0.f;
            float w2 = (e < d2) ? 1.f : 0.f;
            float w3 = (e < d3) ? 1.f : 0.f;
            float4 v0 = x4[s0 * 16 + c4];
            float4 v1 = x4[s1 * 16 + c4];
            float4 v2 = x4[s2 * 16 + c4];
            float4 v3 = x4[s3 * 16 + c4];
            A0.x = fmaf(w0, v0.x, A0.x); A0.y = fmaf(w0, v0.y, A0.y);
            A0.z = fmaf(w0, v0.z, A0.z); A0.w = fmaf(w0, v0.w, A0.w);
            A1.x = fmaf(w1, v1.x, A1.x); A1.y = fmaf(w1, v1.y, A1.y);
            A1.z = fmaf(w1, v1.z, A1.z); A1.w = fmaf(w1, v1.w, A1.w);
            A2.x = fmaf(w2, v2.x, A2.x); A2.y = fmaf(w2, v2.y, A2.y);
            A2.z = fmaf(w2, v2.z, A2.z); A2.w = fmaf(w2, v2.w, A2.w);
            A3.x = fmaf(w3, v3.x, A3.x); A3.y = fmaf(w3, v3.y, A3.y);
            A3.z = fmaf(w3, v3.z, A3.z); A3.w = fmaf(w3, v3.w, A3.w);
        }

        // reduce across the 4 lane-groups (every lane ends with the total)
#define RED4(A) \
        A.x += __shfl_xor(A.x, 32, 64); A.x += __shfl_xor(A.x, 16, 64); \
        A.y += __shfl_xor(A.y, 32, 64); A.y += __shfl_xor(A.y, 16, 64); \
        A.z += __shfl_xor(A.z, 32, 64); A.z += __shfl_xor(A.z, 16, 64); \
        A.w += __shfl_xor(A.w, 32, 64); A.w += __shfl_xor(A.w, 16, 64);
        RED4(A0) RED4(A1) RED4(A2) RED4(A3)
#undef RED4

        float inv0 = 1.0f / fmaxf((float)d0, 1.0f);
        float inv1 = 1.0f / fmaxf((float)d1, 1.0f);
        float inv2 = 1.0f / fmaxf((float)d2, 1.0f);
        float inv3 = 1.0f / fmaxf((float)d3, 1.0f);
        if (lane < 16) {
            sq[w][0][c4] = make_float4(A0.x * inv0, A0.y * inv0, A0.z * inv0, A0.w * inv0);
            sq[w][1][c4] = make_float4(A1.x * inv1, A1.y * inv1, A1.z * inv1, A1.w * inv1);
            sq[w][2][c4] = make_float4(A2.x * inv2, A2.y * inv2, A2.z * inv2, A2.w * inv2);
            sq[w][3][c4] = make_float4(A3.x * inv3, A3.y * inv3, A3.z * inv3, A3.w * inv3);
        }
        sq[w][4 + g][c4] = sv;             // self rows (all 64 lanes)
        // no __syncthreads: same-wave LDS write->read, DS pipe is in-order

        float c0 = bv, c1 = bv, c2 = bv, c3 = bv;
#pragma unroll 4
        for (int k = 0; k < 16; ++k) {     // self part: W[:, 0:64]
            float4 wv = Wq[k * 64 + lane];
            float4 v0 = sq[w][4][k], v1 = sq[w][5][k];
            float4 v2 = sq[w][6][k], v3 = sq[w][7][k];
            c0 = fmaf(wv.x, v0.x, fmaf(wv.y, v0.y, fmaf(wv.z, v0.z, fmaf(wv.w, v0.w, c0))));
            c1 = fmaf(wv.x, v1.x, fmaf(wv.y, v1.y, fmaf(wv.z, v1.z, fmaf(wv.w, v1.w, c1))));
            c2 = fmaf(wv.x, v2.x, fmaf(wv.y, v2.y, fmaf(wv.z, v2.z, fmaf(wv.w, v2.w, c2))));
            c3 = fmaf(wv.x, v3.x, fmaf(wv.y, v3.y, fmaf(wv.z, v3.z, fmaf(wv.w, v3.w, c3))));
        }
#pragma unroll 4
        for (int k = 0; k < 16; ++k) {     // aggr part: W[:, 64:128]
            float4 wv = Wq[(16 + k) * 64 + lane];
            float4 v0 = sq[w][0][k], v1 = sq[w][1][k];
            float4 v2 = sq[w][2][k], v3 = sq[w][3][k];
            c0 = fmaf(wv.x, v0.x, fmaf(wv.y, v0.y, fmaf(wv.z, v0.z, fmaf(wv.w, v0.w, c0))));
            c1 = fmaf(wv.x, v1.x, fmaf(wv.y, v1.y, fmaf(wv.z, v1.z, fmaf(wv.w, v1.w, c1))));
            c2 = fmaf(wv.x, v2.x, fmaf(wv.y, v2.y, fmaf(wv.z, v2.z, fmaf(wv.w, v2.w, c2))));
            c3 = fmaf(wv.x, v3.x, fmaf(wv.y, v3.y, fmaf(wv.z, v3.z, fmaf(wv.w, v3.w, c3))));
        }
        out[(n0 + 0) * NC + lane] = c0;
        out[(n0 + 1) * NC + lane] = c1;
        out[(n0 + 2) * NC + lane] = c2;
        out[(n0 + 3) * NC + lane] = c3;
    }
}

// ---------------------------------------------------------------------------
extern "C" void kernel_launch(void* const* d_in, const int* in_sizes, int n_in,
                              void* d_out, int out_size, void* d_ws, size_t ws_size,
                              hipStream_t stream) {
    const float* x   = (const float*)d_in[0];
    const int*   ei  = (const int*)d_in[1];     // [2, NE] flattened
    const float* W   = (const float*)d_in[2];   // [64, 128]
    const float* b   = (const float*)d_in[3];   // [64]
    float*       out = (float*)d_out;

    const int* row = ei;          // source nodes
    const int* col = ei + NE;     // destination nodes

    // ws layout (ints): cnt[NN] | cursor[NN] | off[NN+1] |
    //                   bsum[196] | boff[196] | perm[NE]   (~3.8 MB total)
    int* cnt    = (int*)d_ws;
    int* cursor = cnt + NN;
    int* off    = cursor + NN;
    int* bsum   = off + NN + 1;
    int* boff   = bsum + 196;
    int* perm   = boff + 196;

    hipMemsetAsync(cnt, 0, 2 * NN * sizeof(int), stream);  // cnt + cursor

    count_kernel<<<(NE / 4 + 255) / 256, 256, 0, stream>>>((const int4*)col, cnt);
    bsum_kernel<<<(NN + 255) / 256, 256, 0, stream>>>(cnt, bsum);
    scan_bsum_kernel<<<1, 256, 0, stream>>>(bsum, boff, (NN + 255) / 256);
    apply_off_kernel<<<(NN + 255) / 256, 256, 0, stream>>>(cnt, boff, off);
    fill_kernel<<<(NE / 4 + 255) / 256, 256, 0, stream>>>(
        (const int4*)row, (const int4*)col, off, cursor, perm);
    gather_linear_kernel<<<GBLK, 256, 0, stream>>>(
        (const float4*)x, off, perm, (const float4*)W, b, out);
}